// Round 1
// baseline (425.362 us; speedup 1.0000x reference)
//
#include <hip/hip_runtime.h>

typedef unsigned short u16;
typedef unsigned int u32;
typedef __attribute__((ext_vector_type(4))) float f32x4;
typedef __attribute__((ext_vector_type(8))) short short8;

#define HWD 56
#define HW2 3136
#define C_IN 128
#define K_OUT 256
#define N_IMG 32
#define CHW_IN 401408   // 128*3136
#define CHW_OUT 802816  // 256*3136
#define PIX 100352      // 32*3136
#define KG 1152         // 128*9
#define WQ_N 294912     // 256*128*9

#define MT 128
#define NT 128
#define KT 32
#define LDP 40          // padded LDS row length (bf16 units); 80B rows -> uniform banks for 16B ops

__device__ __forceinline__ u16 f2bf(float f) {
    u32 u = __float_as_uint(f);
    u32 r = u + 0x7FFFu + ((u >> 16) & 1u);
    return (u16)(r >> 16);
}

__global__ void init_ws(u32* wsmax) {
    if (threadIdx.x == 0) wsmax[0] = 0u;
}

__global__ void maxabs_k(const float* __restrict__ w, u32* __restrict__ wsmax) {
    float m = 0.f;
    for (int i = blockIdx.x * blockDim.x + threadIdx.x; i < WQ_N; i += gridDim.x * blockDim.x)
        m = fmaxf(m, fabsf(w[i]));
    for (int off = 32; off; off >>= 1)
        m = fmaxf(m, __shfl_xor(m, off));
    __shared__ float sm[4];
    int lane = threadIdx.x & 63, wid = threadIdx.x >> 6;
    if (lane == 0) sm[wid] = m;
    __syncthreads();
    if (threadIdx.x == 0) {
        float mm = fmaxf(fmaxf(sm[0], sm[1]), fmaxf(sm[2], sm[3]));
        atomicMax(wsmax, __float_as_uint(mm));  // non-negative floats: uint order == float order
    }
}

__global__ void quant_k(const float* __restrict__ w, const u32* __restrict__ wsmax,
                        u16* __restrict__ wq) {
    int i = blockIdx.x * blockDim.x + threadIdx.x;
    if (i >= WQ_N) return;
    float scale = __uint_as_float(wsmax[0]) / 7.0f;
    float q = rintf(w[i] / scale);          // jnp.round = RNE
    q = fminf(fmaxf(q, -7.0f), 7.0f);
    wq[i] = f2bf(q * scale);
}

// ---- conv as implicit GEMM: out[m][p] = sum_k Wq[m][k] * im2col(x)[k][p]
// A = Wq (256 x 1152 row-major, k = c*9 + r*3 + s). B gathered on the fly.
__global__ __launch_bounds__(256) void conv_gemm(const float* __restrict__ x,
                                                 const u16* __restrict__ wq,
                                                 float* __restrict__ out) {
    __shared__ u16 As[MT * LDP];
    __shared__ u16 Bs[NT * LDP];

    const int tid = threadIdx.x;
    const int lane = tid & 63;
    const int wid = tid >> 6;          // 4 waves: wave grid 2(m) x 2(n)
    const int wm = wid >> 1, wn = wid & 1;
    const int bid = blockIdx.x;        // 1568 blocks: nt-major pairs share B tile in L2
    const int nt = bid >> 1, mt = bid & 1;
    const int pixbase = nt * NT;
    const int mbase = mt * MT;

    // loop-invariant pixel decode for the 2 staged pixels per thread
    int pvalid_base[2], ph[2], pw[2];
    #pragma unroll
    for (int rep = 0; rep < 2; rep++) {
        int i = (tid & 63) + rep * 64;
        int p = pixbase + i;
        int n = p / HW2;
        int hw = p - n * HW2;
        int h = hw / HWD;
        int w = hw - h * HWD;
        ph[rep] = h; pw[rep] = w;
        pvalid_base[rep] = n * CHW_IN + (h - 1) * HWD + (w - 1); // + c*HW2 + r*56 + s
    }
    const int kk0 = wid * 8;   // each wave stages one 8-k octet for all 128 pixels

    f32x4 acc[4][4];
    #pragma unroll
    for (int a = 0; a < 4; a++)
        #pragma unroll
        for (int b = 0; b < 4; b++)
            acc[a][b] = (f32x4){0.f, 0.f, 0.f, 0.f};

    for (int kt = 0; kt < KG / KT; kt++) {
        const int kbase = kt * KT;
        __syncthreads();
        // ---- stage A: 128 rows x 32 k, 16B per thread-op, 2 ops
        #pragma unroll
        for (int rep = 0; rep < 2; rep++) {
            int L = tid + rep * 256;
            int m = L >> 2;
            int o = L & 3;
            const u16* src = wq + (mbase + m) * KG + kbase + o * 8;
            uint4 v = *(const uint4*)src;
            *(uint4*)&As[m * LDP + o * 8] = v;
        }
        // ---- stage B: gather im2col, pack 8 bf16, one ds_write_b128 per pixel
        #pragma unroll
        for (int rep = 0; rep < 2; rep++) {
            int i = (tid & 63) + rep * 64;
            union { u16 us[8]; uint4 v4; } pk;
            #pragma unroll
            for (int j = 0; j < 8; j++) {
                int kk = kbase + kk0 + j;
                int c = kk / 9;
                int rs = kk - c * 9;
                int r = rs / 3;
                int s = rs - r * 3;
                int ih = ph[rep] + r - 1;
                int iw = pw[rep] + s - 1;
                float v = 0.f;
                if ((u32)ih < (u32)HWD && (u32)iw < (u32)HWD)
                    v = x[pvalid_base[rep] + c * HW2 + r * HWD + s];
                pk.us[j] = f2bf(v);
            }
            *(uint4*)&Bs[i * LDP + kk0] = pk.v4;
        }
        __syncthreads();
        // ---- fragments + MFMA. A: lane holds A[m=lane&15][k=(lane>>4)*8 + j]
        short8 af[4], bfr[4];
        const int fr = lane & 15, fq = lane >> 4;
        #pragma unroll
        for (int mi = 0; mi < 4; mi++)
            af[mi] = *(const short8*)&As[(wm * 64 + mi * 16 + fr) * LDP + fq * 8];
        #pragma unroll
        for (int ni = 0; ni < 4; ni++)
            bfr[ni] = *(const short8*)&Bs[(wn * 64 + ni * 16 + fr) * LDP + fq * 8];
        #pragma unroll
        for (int mi = 0; mi < 4; mi++)
            #pragma unroll
            for (int ni = 0; ni < 4; ni++)
                acc[mi][ni] = __builtin_amdgcn_mfma_f32_16x16x32_bf16(
                    af[mi], bfr[ni], acc[mi][ni], 0, 0, 0);
    }

    // ---- epilogue: C/D layout col=lane&15 (pixel), row=(lane>>4)*4+j (channel)
    const int fr = lane & 15, fq = lane >> 4;
    #pragma unroll
    for (int ni = 0; ni < 4; ni++) {
        int pix = pixbase + wn * 64 + ni * 16 + fr;
        int n = pix / HW2;
        int hw = pix - n * HW2;
        int obase = n * CHW_OUT + hw;
        #pragma unroll
        for (int mi = 0; mi < 4; mi++) {
            int ch = mbase + wm * 64 + mi * 16 + fq * 4;
            #pragma unroll
            for (int j = 0; j < 4; j++)
                out[obase + (ch + j) * HW2] = acc[mi][ni][j];
        }
    }
}

// ---- per-channel batch stats -> {inv, shift}
__global__ void stats_k(const float* __restrict__ out, const float* __restrict__ gamma,
                        const float* __restrict__ beta, float* __restrict__ stats) {
    int ch = blockIdx.x;
    int tid = threadIdx.x;
    float s = 0.f, sq = 0.f;
    const float* base = out + ch * HW2;
    for (int n = 0; n < N_IMG; n++) {
        const float* p = base + n * CHW_OUT;
        for (int hw = tid; hw < HW2; hw += 256) {
            float v = p[hw];
            s += v; sq += v * v;
        }
    }
    for (int off = 32; off; off >>= 1) {
        s += __shfl_xor(s, off);
        sq += __shfl_xor(sq, off);
    }
    __shared__ float ss[4], ssq[4];
    int lane = tid & 63, wid = tid >> 6;
    if (lane == 0) { ss[wid] = s; ssq[wid] = sq; }
    __syncthreads();
    if (tid == 0) {
        float ts = ss[0] + ss[1] + ss[2] + ss[3];
        float tsq = ssq[0] + ssq[1] + ssq[2] + ssq[3];
        const float cnt = (float)PIX;
        float mean = ts / cnt;
        float var = tsq / cnt - mean * mean;
        float inv = gamma[ch] * rsqrtf(var + 1e-5f);
        stats[2 * ch] = inv;
        stats[2 * ch + 1] = beta[ch] - mean * inv;
    }
}

__global__ void bn_relu_k(float* __restrict__ out, const float* __restrict__ stats) {
    const int n4 = (N_IMG * CHW_OUT) / 4;
    int stride = gridDim.x * blockDim.x;
    for (int i = blockIdx.x * blockDim.x + threadIdx.x; i < n4; i += stride) {
        int ch = (i / (HW2 / 4)) & (K_OUT - 1);
        float inv = stats[2 * ch], sh = stats[2 * ch + 1];
        f32x4 v = ((f32x4*)out)[i];
        #pragma unroll
        for (int j = 0; j < 4; j++)
            v[j] = fmaxf(v[j] * inv + sh, 0.f);
        ((f32x4*)out)[i] = v;
    }
}

extern "C" void kernel_launch(void* const* d_in, const int* in_sizes, int n_in,
                              void* d_out, int out_size, void* d_ws, size_t ws_size,
                              hipStream_t stream) {
    const float* x = (const float*)d_in[0];
    const float* w = (const float*)d_in[1];
    const float* gamma = (const float*)d_in[2];
    const float* beta = (const float*)d_in[3];
    float* out = (float*)d_out;

    u32* wsmax = (u32*)d_ws;
    u16* wq = (u16*)((char*)d_ws + 64);
    float* stats = (float*)((char*)d_ws + 64 + WQ_N * 2);  // 589888, 64B-aligned

    init_ws<<<1, 64, 0, stream>>>(wsmax);
    maxabs_k<<<128, 256, 0, stream>>>(w, wsmax);
    quant_k<<<WQ_N / 256, 256, 0, stream>>>(w, wsmax, wq);
    conv_gemm<<<(K_OUT / MT) * (PIX / NT), 256, 0, stream>>>(x, wq, out);
    stats_k<<<K_OUT, 256, 0, stream>>>(out, gamma, beta, stats);
    bn_relu_k<<<4096, 256, 0, stream>>>(out, stats);
}

// Round 2
// 219.104 us; speedup vs baseline: 1.9414x; 1.9414x over previous
//
#include <hip/hip_runtime.h>

typedef unsigned short u16;
typedef unsigned int u32;
typedef __attribute__((ext_vector_type(4))) float f32x4;
typedef __attribute__((ext_vector_type(8))) short short8;

#define HWD 56
#define HW2 3136
#define C_IN 128
#define K_OUT 256
#define N_IMG 32
#define CHW_IN 401408   // 128*3136
#define CHW_OUT 802816  // 256*3136
#define PIX 100352      // 32*3136
#define KG 1152         // 128*9
#define WQ_N 294912     // 256*128*9
#define XP 58
#define XPP 3364        // 58*58
#define XT_PER_N (XPP*128)      // 430592 elems per image
#define XT_BYTES (32u*XT_PER_N*2u)  // 27,557,888
#define NTILES 784      // PIX/128

__device__ __forceinline__ u16 f2bf(float f) {
    u32 u = __float_as_uint(f);
    u32 r = u + 0x7FFFu + ((u >> 16) & 1u);
    return (u16)(r >> 16);
}

__device__ __forceinline__ void glds16(const u16* g, u16* l) {
    __builtin_amdgcn_global_load_lds(
        (const __attribute__((address_space(1))) void*)g,
        (__attribute__((address_space(3))) void*)l, 16, 0, 0);
}

__global__ void maxabs_k(const float* __restrict__ w, u32* __restrict__ wsmax) {
    float m = 0.f;
    for (int i = blockIdx.x * blockDim.x + threadIdx.x; i < WQ_N; i += gridDim.x * blockDim.x)
        m = fmaxf(m, fabsf(w[i]));
    for (int off = 32; off; off >>= 1)
        m = fmaxf(m, __shfl_xor(m, off));
    __shared__ float sm[4];
    int lane = threadIdx.x & 63, wid = threadIdx.x >> 6;
    if (lane == 0) sm[wid] = m;
    __syncthreads();
    if (threadIdx.x == 0) {
        float mm = fmaxf(fmaxf(sm[0], sm[1]), fmaxf(sm[2], sm[3]));
        atomicMax(wsmax, __float_as_uint(mm));
    }
}

// wqt[tap][m][c] = quantized w[m][c][tap], bf16
__global__ void quant_t_k(const float* __restrict__ w, const u32* __restrict__ wsmax,
                          u16* __restrict__ wqt) {
    int o = blockIdx.x * 256 + threadIdx.x;
    if (o >= WQ_N) return;
    int c = o & 127;
    int mm = o >> 7;
    int tap = mm >> 8;
    int m = mm & 255;
    float scale = __uint_as_float(wsmax[0]) / 7.0f;
    float q = rintf(w[(m * 128 + c) * 9 + tap] / scale);
    q = fminf(fmaxf(q, -7.0f), 7.0f);
    wqt[o] = f2bf(q * scale);
}

// x (NCHW f32) -> xt (N,58,58,C) bf16, zero-padded borders (buffer pre-memset)
__global__ __launch_bounds__(256) void pad_transpose(const float* __restrict__ x,
                                                     u16* __restrict__ xt) {
    __shared__ float T[128][57];
    const int tid = threadIdx.x;
    const int n = blockIdx.x / HWD;
    const int h = blockIdx.x - n * HWD;
    const float* src = x + (size_t)n * CHW_IN + h * HWD;
    #pragma unroll
    for (int it = 0; it < 7; ++it) {
        int i = tid + it * 256;            // i in [0, 128*14)
        int c = i / 14, q = i - c * 14;
        float4 v = *(const float4*)(src + c * HW2 + q * 4);
        T[c][q * 4 + 0] = v.x; T[c][q * 4 + 1] = v.y;
        T[c][q * 4 + 2] = v.z; T[c][q * 4 + 3] = v.w;
    }
    __syncthreads();
    u16* dst = xt + ((size_t)n * XPP + (h + 1) * XP + 1) * 128;
    #pragma unroll
    for (int it = 0; it < 4; ++it) {
        int i = tid + it * 256;            // i in [0, 56*16)
        if (i < 56 * 16) {
            int w = i >> 4, oc = i & 15;
            union { u16 us[8]; uint4 v4; } pk;
            #pragma unroll
            for (int j = 0; j < 8; ++j) pk.us[j] = f2bf(T[oc * 8 + j][w]);
            *(uint4*)(dst + (size_t)w * 128 + oc * 8) = pk.v4;
        }
    }
}

// implicit GEMM, NHWC input: out[m][p] = sum_{tap,c} wqt[tap][m][c] * xt[pix(p)+tap][c]
__global__ __launch_bounds__(256, 4) void conv_nhwc(const u16* __restrict__ xt,
                                                    const u16* __restrict__ wqt,
                                                    float* __restrict__ out,
                                                    float* __restrict__ P) {
    __shared__ u16 As[4][128][8];   // [k-octet][m][8 bf16] = 8KB
    __shared__ u16 Bs[4][128][8];   // [k-octet][pixel][8 bf16]
    const int tid = threadIdx.x;
    const int lane = tid & 63;
    const int wid = tid >> 6;
    const int wm = wid >> 1, wn = wid & 1;
    const int nt = blockIdx.x >> 1, mt = blockIdx.x & 1;  // mt-pairs adjacent: share B in cache
    const int pixbase = nt * 128, mbase = mt * 128;

    // staging roles: wave stages rows [sblk*64, +64) of k-octets {sfq0, sfq0+1}
    const int sblk = wid & 1;
    const int sfq0 = (wid >> 1) * 2;

    const u16* aG = wqt + (mbase + sblk * 64 + lane) * 128;  // + tap*32768 + cc*32 + fq*8
    const u16* bG;
    {
        int p = pixbase + sblk * 64 + lane;
        int n = p / HW2;
        int hw = p - n * HW2;
        int h = hw / HWD;
        int w = hw - h * HWD;
        bG = xt + (size_t)n * XT_PER_N + (h * XP + w) * 128;  // + (r*58+s)*128 + cc*32 + fq*8
    }

    f32x4 acc[4][4];
    #pragma unroll
    for (int a = 0; a < 4; ++a)
        #pragma unroll
        for (int b = 0; b < 4; ++b)
            acc[a][b] = (f32x4){0.f, 0.f, 0.f, 0.f};

    const int fr = lane & 15, fq = lane >> 4;

    for (int kt = 0; kt < 36; ++kt) {
        const int tap = kt >> 2, cc = kt & 3;
        const int r = tap / 3, s = tap - r * 3;
        const int toff = (r * XP + s) * 128 + cc * 32;
        const int aoff = tap * 32768 + cc * 32;
        __syncthreads();
        glds16(aG + aoff + (sfq0 + 0) * 8, &As[sfq0 + 0][sblk * 64][0]);
        glds16(aG + aoff + (sfq0 + 1) * 8, &As[sfq0 + 1][sblk * 64][0]);
        glds16(bG + toff + (sfq0 + 0) * 8, &Bs[sfq0 + 0][sblk * 64][0]);
        glds16(bG + toff + (sfq0 + 1) * 8, &Bs[sfq0 + 1][sblk * 64][0]);
        __syncthreads();   // compiler drains vmcnt(0) before barrier
        short8 af[4], bf[4];
        #pragma unroll
        for (int mi = 0; mi < 4; ++mi)
            af[mi] = *(const short8*)&As[fq][wm * 64 + mi * 16 + fr][0];
        #pragma unroll
        for (int ni = 0; ni < 4; ++ni)
            bf[ni] = *(const short8*)&Bs[fq][wn * 64 + ni * 16 + fr][0];
        #pragma unroll
        for (int mi = 0; mi < 4; ++mi)
            #pragma unroll
            for (int ni = 0; ni < 4; ++ni)
                acc[mi][ni] = __builtin_amdgcn_mfma_f32_16x16x32_bf16(
                    af[mi], bf[ni], acc[mi][ni], 0, 0, 0);
    }

    // epilogue: C/D layout col(lane&15)=pixel, row((lane>>4)*4+j)=channel
    #pragma unroll
    for (int ni = 0; ni < 4; ++ni) {
        int pix = pixbase + wn * 64 + ni * 16 + fr;
        int n = pix / HW2;
        int hw = pix - n * HW2;
        int obase = n * CHW_OUT + hw;
        #pragma unroll
        for (int mi = 0; mi < 4; ++mi) {
            int ch = mbase + wm * 64 + mi * 16 + fq * 4;
            #pragma unroll
            for (int j = 0; j < 4; ++j)
                out[obase + (ch + j) * HW2] = acc[mi][ni][j];
        }
    }

    // fused per-channel partial sums over this wave's 64 pixels
    #pragma unroll
    for (int mi = 0; mi < 4; ++mi) {
        #pragma unroll
        for (int j = 0; j < 4; ++j) {
            float s = 0.f, q = 0.f;
            #pragma unroll
            for (int ni = 0; ni < 4; ++ni) {
                float v = acc[mi][ni][j];
                s += v; q += v * v;
            }
            #pragma unroll
            for (int msk = 1; msk < 16; msk <<= 1) {
                s += __shfl_xor(s, msk);
                q += __shfl_xor(q, msk);
            }
            if (fr == 0) {
                int ch = mbase + wm * 64 + mi * 16 + fq * 4 + j;
                float* dst = P + ((size_t)(nt * 2 + wn) * 256 + ch) * 2;
                dst[0] = s; dst[1] = q;
            }
        }
    }
}

__global__ void stats_fin(const float* __restrict__ P, const float* __restrict__ gamma,
                          const float* __restrict__ beta, float* __restrict__ stats) {
    int ch = blockIdx.x;
    int tid = threadIdx.x;
    float s = 0.f, q = 0.f;
    for (int i = tid; i < NTILES * 2; i += 256) {
        const float* p = P + ((size_t)i * 256 + ch) * 2;
        s += p[0]; q += p[1];
    }
    for (int m = 32; m; m >>= 1) { s += __shfl_xor(s, m); q += __shfl_xor(q, m); }
    __shared__ float ss[4], qs[4];
    int l = tid & 63, w = tid >> 6;
    if (l == 0) { ss[w] = s; qs[w] = q; }
    __syncthreads();
    if (tid == 0) {
        float S = ss[0] + ss[1] + ss[2] + ss[3];
        float Q = qs[0] + qs[1] + qs[2] + qs[3];
        float mean = S / (float)PIX;
        float var = Q / (float)PIX - mean * mean;
        float inv = gamma[ch] * rsqrtf(var + 1e-5f);
        stats[2 * ch] = inv;
        stats[2 * ch + 1] = beta[ch] - mean * inv;
    }
}

__global__ void bn_relu_k(float* __restrict__ out, const float* __restrict__ stats) {
    const int n4 = (N_IMG * CHW_OUT) / 4;
    int stride = gridDim.x * blockDim.x;
    for (int i = blockIdx.x * blockDim.x + threadIdx.x; i < n4; i += stride) {
        int ch = (i / (HW2 / 4)) & (K_OUT - 1);
        float inv = stats[2 * ch], sh = stats[2 * ch + 1];
        f32x4 v = ((f32x4*)out)[i];
        #pragma unroll
        for (int j = 0; j < 4; ++j)
            v[j] = fmaxf(v[j] * inv + sh, 0.f);
        ((f32x4*)out)[i] = v;
    }
}

extern "C" void kernel_launch(void* const* d_in, const int* in_sizes, int n_in,
                              void* d_out, int out_size, void* d_ws, size_t ws_size,
                              hipStream_t stream) {
    const float* x = (const float*)d_in[0];
    const float* w = (const float*)d_in[1];
    const float* gamma = (const float*)d_in[2];
    const float* beta = (const float*)d_in[3];
    float* out = (float*)d_out;

    char* ws = (char*)d_ws;
    u32* wsmax = (u32*)ws;                         // [0, 64)
    float* stats = (float*)(ws + 64);              // 2KB
    u16* wqt = (u16*)(ws + 4096);                  // 589,824 B
    u16* xt = (u16*)(ws + (1u << 20));             // 27,557,888 B
    float* P = (float*)(ws + 29360128u);           // 3,211,264 B  (total ~32.6MB)

    hipMemsetAsync(wsmax, 0, 64, stream);
    hipMemsetAsync(xt, 0, XT_BYTES, stream);
    maxabs_k<<<128, 256, 0, stream>>>(w, wsmax);
    quant_t_k<<<WQ_N / 256, 256, 0, stream>>>(w, wsmax, wqt);
    pad_transpose<<<N_IMG * HWD, 256, 0, stream>>>(x, xt);
    conv_nhwc<<<NTILES * 2, 256, 0, stream>>>(xt, wqt, out, P);
    stats_fin<<<K_OUT, 256, 0, stream>>>(P, gamma, beta, stats);
    bn_relu_k<<<4096, 256, 0, stream>>>(out, stats);
}

// Round 3
// 208.267 us; speedup vs baseline: 2.0424x; 1.0520x over previous
//
#include <hip/hip_runtime.h>

typedef unsigned short u16;
typedef unsigned int u32;
typedef __attribute__((ext_vector_type(4))) float f32x4;
typedef __attribute__((ext_vector_type(8))) short short8;

#define HWD 56
#define HW2 3136
#define C_IN 128
#define K_OUT 256
#define N_IMG 32
#define CHW_IN 401408   // 128*3136
#define CHW_OUT 802816  // 256*3136
#define PIX 100352      // 32*3136
#define KG 1152         // 128*9
#define WQ_N 294912     // 256*128*9
#define XP 58
#define XPP 3364        // 58*58
#define XT_PER_N (XPP*128)          // 430592 elems per image
#define XT_BYTES (32u*XT_PER_N*2u)  // 27,557,888
#define NTILES 784      // PIX/128

__device__ __forceinline__ u16 f2bf(float f) {
    u32 u = __float_as_uint(f);
    u32 r = u + 0x7FFFu + ((u >> 16) & 1u);
    return (u16)(r >> 16);
}

__device__ __forceinline__ void glds16(const u16* g, u16* l) {
    __builtin_amdgcn_global_load_lds(
        (const __attribute__((address_space(1))) void*)g,
        (__attribute__((address_space(3))) void*)l, 16, 0, 0);
}

__global__ void maxabs_k(const float* __restrict__ w, u32* __restrict__ wsmax) {
    float m = 0.f;
    for (int i = blockIdx.x * blockDim.x + threadIdx.x; i < WQ_N; i += gridDim.x * blockDim.x)
        m = fmaxf(m, fabsf(w[i]));
    for (int off = 32; off; off >>= 1)
        m = fmaxf(m, __shfl_xor(m, off));
    __shared__ float sm[4];
    int lane = threadIdx.x & 63, wid = threadIdx.x >> 6;
    if (lane == 0) sm[wid] = m;
    __syncthreads();
    if (threadIdx.x == 0) {
        float mm = fmaxf(fmaxf(sm[0], sm[1]), fmaxf(sm[2], sm[3]));
        atomicMax(wsmax, __float_as_uint(mm));
    }
}

// wqt[tap][m][c] = quantized w[m][c][tap], bf16
__global__ void quant_t_k(const float* __restrict__ w, const u32* __restrict__ wsmax,
                          u16* __restrict__ wqt) {
    int o = blockIdx.x * 256 + threadIdx.x;
    if (o >= WQ_N) return;
    int c = o & 127;
    int mm = o >> 7;
    int tap = mm >> 8;
    int m = mm & 255;
    float scale = __uint_as_float(wsmax[0]) / 7.0f;
    float q = rintf(w[(m * 128 + c) * 9 + tap] / scale);
    q = fminf(fmaxf(q, -7.0f), 7.0f);
    wqt[o] = f2bf(q * scale);
}

// x (NCHW f32) -> xt (N,58,58,C) bf16, zero-padded borders (buffer pre-memset)
__global__ __launch_bounds__(256) void pad_transpose(const float* __restrict__ x,
                                                     u16* __restrict__ xt) {
    __shared__ float T[128][57];
    const int tid = threadIdx.x;
    const int n = blockIdx.x / HWD;
    const int h = blockIdx.x - n * HWD;
    const float* src = x + (size_t)n * CHW_IN + h * HWD;
    #pragma unroll
    for (int it = 0; it < 7; ++it) {
        int i = tid + it * 256;            // i in [0, 128*14)
        int c = i / 14, q = i - c * 14;
        float4 v = *(const float4*)(src + c * HW2 + q * 4);
        T[c][q * 4 + 0] = v.x; T[c][q * 4 + 1] = v.y;
        T[c][q * 4 + 2] = v.z; T[c][q * 4 + 3] = v.w;
    }
    __syncthreads();
    u16* dst = xt + ((size_t)n * XPP + (h + 1) * XP + 1) * 128;
    #pragma unroll
    for (int it = 0; it < 4; ++it) {
        int i = tid + it * 256;            // i in [0, 56*16)
        if (i < 56 * 16) {
            int w = i >> 4, oc = i & 15;
            union { u16 us[8]; uint4 v4; } pk;
            #pragma unroll
            for (int j = 0; j < 8; ++j) pk.us[j] = f2bf(T[oc * 8 + j][w]);
            *(uint4*)(dst + (size_t)w * 128 + oc * 8) = pk.v4;
        }
    }
}

// implicit GEMM, NHWC input, depth-1 prefetch double-buffer (T3-minimal),
// one __syncthreads per K-step (its vmcnt(0) drain lands after ~full compute phase).
__global__ __launch_bounds__(256, 4) void conv_nhwc(const u16* __restrict__ xt,
                                                    const u16* __restrict__ wqt,
                                                    float* __restrict__ out,
                                                    float* __restrict__ P) {
    __shared__ u16 As[2][4][128][8];   // [buf][k-octet][m][8 bf16] = 16KB
    __shared__ u16 Bs[2][4][128][8];   // [buf][k-octet][pixel][8 bf16] = 16KB
    const int tid = threadIdx.x;
    const int lane = tid & 63;
    const int wid = tid >> 6;
    const int wm = wid >> 1, wn = wid & 1;

    // T1: XCD-aware swizzle. 1568 blocks, 8 XCDs, 196 per XCD (divisible -> bijective).
    const int swz = (blockIdx.x & 7) * 196 + (blockIdx.x >> 3);
    const int nt = swz >> 1, mt = swz & 1;  // mt-pair adjacent on same XCD: shares B tile in L2
    const int pixbase = nt * 128, mbase = mt * 128;

    // staging roles: wave stages rows [sblk*64, +64) of k-octets {sfq0, sfq0+1}
    const int sblk = wid & 1;
    const int sfq0 = (wid >> 1) * 2;

    const u16* aG = wqt + (mbase + sblk * 64 + lane) * 128;  // + tap*32768 + cc*32 + oct*8
    const u16* bG;
    {
        int p = pixbase + sblk * 64 + lane;
        int n = p / HW2;
        int hw = p - n * HW2;
        int h = hw / HWD;
        int w = hw - h * HWD;
        bG = xt + (size_t)n * XT_PER_N + (h * XP + w) * 128;  // + (r*58+s)*128 + cc*32 + oct*8
    }

#define STAGE(buf, aoff, toff) do {                                          \
        glds16(aG + (aoff) + (sfq0 + 0) * 8, &As[buf][sfq0 + 0][sblk * 64][0]); \
        glds16(aG + (aoff) + (sfq0 + 1) * 8, &As[buf][sfq0 + 1][sblk * 64][0]); \
        glds16(bG + (toff) + (sfq0 + 0) * 8, &Bs[buf][sfq0 + 0][sblk * 64][0]); \
        glds16(bG + (toff) + (sfq0 + 1) * 8, &Bs[buf][sfq0 + 1][sblk * 64][0]); \
    } while (0)

    f32x4 acc[4][4];
    #pragma unroll
    for (int a = 0; a < 4; ++a)
        #pragma unroll
        for (int b = 0; b < 4; ++b)
            acc[a][b] = (f32x4){0.f, 0.f, 0.f, 0.f};

    const int fr = lane & 15, fq = lane >> 4;

    STAGE(0, 0, 0);        // kt=0: tap 0 (r=0,s=0), cc=0
    __syncthreads();

    int cur = 0;
    #pragma unroll 2
    for (int kt = 0; kt < 36; ++kt) {
        if (kt + 1 < 36) {
            const int kt2 = kt + 1;
            const int tap2 = kt2 >> 2, cc2 = kt2 & 3;
            const int r2 = tap2 / 3, s2 = tap2 - r2 * 3;
            STAGE(cur ^ 1, tap2 * 32768 + cc2 * 32, (r2 * XP + s2) * 128 + cc2 * 32);
        }
        short8 af[4], bf[4];
        #pragma unroll
        for (int mi = 0; mi < 4; ++mi)
            af[mi] = *(const short8*)&As[cur][fq][wm * 64 + mi * 16 + fr][0];
        #pragma unroll
        for (int ni = 0; ni < 4; ++ni)
            bf[ni] = *(const short8*)&Bs[cur][fq][wn * 64 + ni * 16 + fr][0];
        __builtin_amdgcn_s_setprio(1);
        #pragma unroll
        for (int mi = 0; mi < 4; ++mi)
            #pragma unroll
            for (int ni = 0; ni < 4; ++ni)
                acc[mi][ni] = __builtin_amdgcn_mfma_f32_16x16x32_bf16(
                    af[mi], bf[ni], acc[mi][ni], 0, 0, 0);
        __builtin_amdgcn_s_setprio(0);
        __syncthreads();   // drains vmcnt(0): next-tile loads had the whole compute to land
        cur ^= 1;
    }
#undef STAGE

    // epilogue: C/D layout col(lane&15)=pixel, row((lane>>4)*4+j)=channel
    #pragma unroll
    for (int ni = 0; ni < 4; ++ni) {
        int pix = pixbase + wn * 64 + ni * 16 + fr;
        int n = pix / HW2;
        int hw = pix - n * HW2;
        int obase = n * CHW_OUT + hw;
        #pragma unroll
        for (int mi = 0; mi < 4; ++mi) {
            int ch = mbase + wm * 64 + mi * 16 + fq * 4;
            #pragma unroll
            for (int j = 0; j < 4; ++j)
                out[obase + (ch + j) * HW2] = acc[mi][ni][j];
        }
    }

    // fused per-channel partial sums over this wave's 64 pixels
    #pragma unroll
    for (int mi = 0; mi < 4; ++mi) {
        #pragma unroll
        for (int j = 0; j < 4; ++j) {
            float s = 0.f, q = 0.f;
            #pragma unroll
            for (int ni = 0; ni < 4; ++ni) {
                float v = acc[mi][ni][j];
                s += v; q += v * v;
            }
            #pragma unroll
            for (int msk = 1; msk < 16; msk <<= 1) {
                s += __shfl_xor(s, msk);
                q += __shfl_xor(q, msk);
            }
            if (fr == 0) {
                int ch = mbase + wm * 64 + mi * 16 + fq * 4 + j;
                float* dst = P + ((size_t)(nt * 2 + wn) * 256 + ch) * 2;
                dst[0] = s; dst[1] = q;
            }
        }
    }
}

__global__ void stats_fin(const float* __restrict__ P, const float* __restrict__ gamma,
                          const float* __restrict__ beta, float* __restrict__ stats) {
    int ch = blockIdx.x;
    int tid = threadIdx.x;
    float s = 0.f, q = 0.f;
    for (int i = tid; i < NTILES * 2; i += 256) {
        const float* p = P + ((size_t)i * 256 + ch) * 2;
        s += p[0]; q += p[1];
    }
    for (int m = 32; m; m >>= 1) { s += __shfl_xor(s, m); q += __shfl_xor(q, m); }
    __shared__ float ss[4], qs[4];
    int l = tid & 63, w = tid >> 6;
    if (l == 0) { ss[w] = s; qs[w] = q; }
    __syncthreads();
    if (tid == 0) {
        float S = ss[0] + ss[1] + ss[2] + ss[3];
        float Q = qs[0] + qs[1] + qs[2] + qs[3];
        float mean = S / (float)PIX;
        float var = Q / (float)PIX - mean * mean;
        float inv = gamma[ch] * rsqrtf(var + 1e-5f);
        stats[2 * ch] = inv;
        stats[2 * ch + 1] = beta[ch] - mean * inv;
    }
}

__global__ void bn_relu_k(float* __restrict__ out, const float* __restrict__ stats) {
    const int n4 = (N_IMG * CHW_OUT) / 4;
    int stride = gridDim.x * blockDim.x;
    for (int i = blockIdx.x * blockDim.x + threadIdx.x; i < n4; i += stride) {
        int ch = (i / (HW2 / 4)) & (K_OUT - 1);
        float inv = stats[2 * ch], sh = stats[2 * ch + 1];
        f32x4 v = ((f32x4*)out)[i];
        #pragma unroll
        for (int j = 0; j < 4; ++j)
            v[j] = fmaxf(v[j] * inv + sh, 0.f);
        ((f32x4*)out)[i] = v;
    }
}

extern "C" void kernel_launch(void* const* d_in, const int* in_sizes, int n_in,
                              void* d_out, int out_size, void* d_ws, size_t ws_size,
                              hipStream_t stream) {
    const float* x = (const float*)d_in[0];
    const float* w = (const float*)d_in[1];
    const float* gamma = (const float*)d_in[2];
    const float* beta = (const float*)d_in[3];
    float* out = (float*)d_out;

    char* ws = (char*)d_ws;
    u32* wsmax = (u32*)ws;                         // [0, 64)
    float* stats = (float*)(ws + 64);              // 2KB
    u16* wqt = (u16*)(ws + 4096);                  // 589,824 B
    u16* xt = (u16*)(ws + (1u << 20));             // 27,557,888 B
    float* P = (float*)(ws + 29360128u);           // 3,211,264 B  (total ~32.6MB)

    hipMemsetAsync(wsmax, 0, 64, stream);
    hipMemsetAsync(xt, 0, XT_BYTES, stream);
    maxabs_k<<<128, 256, 0, stream>>>(w, wsmax);
    quant_t_k<<<WQ_N / 256, 256, 0, stream>>>(w, wsmax, wqt);
    pad_transpose<<<N_IMG * HWD, 256, 0, stream>>>(x, xt);
    conv_nhwc<<<NTILES * 2, 256, 0, stream>>>(xt, wqt, out, P);
    stats_fin<<<K_OUT, 256, 0, stream>>>(P, gamma, beta, stats);
    bn_relu_k<<<4096, 256, 0, stream>>>(out, stats);
}

// Round 4
// 161.060 us; speedup vs baseline: 2.6410x; 1.2931x over previous
//
#include <hip/hip_runtime.h>

typedef unsigned short u16;
typedef unsigned int u32;
typedef __attribute__((ext_vector_type(4))) float f32x4;
typedef __attribute__((ext_vector_type(8))) short short8;

#define HWD 56
#define HW2 3136
#define C_IN 128
#define K_OUT 256
#define N_IMG 32
#define CHW_IN 401408   // 128*3136
#define CHW_OUT 802816  // 256*3136
#define PIX 100352      // 32*3136
#define WQ_N 294912     // 256*128*9
#define XP 58
#define XPP 3364        // 58*58
#define XT_PER_N (XPP*128)          // 430592 elems per image
#define NT2 1568        // stats slices: 392 blocks * 4 wn

__device__ __forceinline__ u16 f2bf(float f) {
    u32 u = __float_as_uint(f);
    u32 r = u + 0x7FFFu + ((u >> 16) & 1u);
    return (u16)(r >> 16);
}

__device__ __forceinline__ void glds16(const u16* g, u16* l) {
    __builtin_amdgcn_global_load_lds(
        (const __attribute__((address_space(1))) void*)g,
        (__attribute__((address_space(3))) void*)l, 16, 0, 0);
}

__global__ void maxabs_k(const float* __restrict__ w, u32* __restrict__ wsmax) {
    float m = 0.f;
    for (int i = blockIdx.x * blockDim.x + threadIdx.x; i < WQ_N; i += gridDim.x * blockDim.x)
        m = fmaxf(m, fabsf(w[i]));
    for (int off = 32; off; off >>= 1)
        m = fmaxf(m, __shfl_xor(m, off));
    __shared__ float sm[4];
    int lane = threadIdx.x & 63, wid = threadIdx.x >> 6;
    if (lane == 0) sm[wid] = m;
    __syncthreads();
    if (threadIdx.x == 0) {
        float mm = fmaxf(fmaxf(sm[0], sm[1]), fmaxf(sm[2], sm[3]));
        atomicMax(wsmax, __float_as_uint(mm));
    }
}

// wqt2 layout: [kt(18)][oct8][m(256)][8] — matches conv LDS A layout exactly.
// k-tile kt = tap*2 + chalf; k_in_tile = (oct8>>2)*32 + (oct8&3)*8 + j; c = (kt&1)*64 + k_in_tile
__global__ void quant_t_k(const float* __restrict__ w, const u32* __restrict__ wsmax,
                          u16* __restrict__ wqt2) {
    int o = blockIdx.x * 256 + threadIdx.x;
    if (o >= WQ_N) return;
    int j = o & 7;
    int t = o >> 3;
    int m = t & 255;
    int t2 = t >> 8;
    int oct8 = t2 & 7;
    int kt = t2 >> 3;
    int c = (kt & 1) * 64 + (oct8 >> 2) * 32 + (oct8 & 3) * 8 + j;
    int tap = kt >> 1;
    float scale = __uint_as_float(wsmax[0]) / 7.0f;
    float q = rintf(w[(m * 128 + c) * 9 + tap] / scale);
    q = fminf(fmaxf(q, -7.0f), 7.0f);
    wqt2[o] = f2bf(q * scale);
}

// zero only the 1-pixel halo of xt (interior fully written by pad_transpose)
__global__ void halo_zero(u16* __restrict__ xt) {
    int i = blockIdx.x * 256 + threadIdx.x;   // one 16B chunk
    if (i >= 32 * 3648) return;
    int n = i / 3648, t = i - n * 3648;
    int site = t >> 4, chunk = t & 15;
    int h, w;
    if (site < 58)       { h = 0;          w = site; }
    else if (site < 116) { h = 57;         w = site - 58; }
    else if (site < 172) { h = site - 115; w = 0; }
    else                 { h = site - 171; w = 57; }
    *(uint4*)(xt + ((size_t)n * XPP + h * XP + w) * 128 + chunk * 8) = (uint4){0, 0, 0, 0};
}

// x (NCHW f32) -> xt (N,58,58,C) bf16 interior
__global__ __launch_bounds__(256) void pad_transpose(const float* __restrict__ x,
                                                     u16* __restrict__ xt) {
    __shared__ float T[128][57];
    const int tid = threadIdx.x;
    const int n = blockIdx.x / HWD;
    const int h = blockIdx.x - n * HWD;
    const float* src = x + (size_t)n * CHW_IN + h * HWD;
    #pragma unroll
    for (int it = 0; it < 7; ++it) {
        int i = tid + it * 256;
        int c = i / 14, q = i - c * 14;
        float4 v = *(const float4*)(src + c * HW2 + q * 4);
        T[c][q * 4 + 0] = v.x; T[c][q * 4 + 1] = v.y;
        T[c][q * 4 + 2] = v.z; T[c][q * 4 + 3] = v.w;
    }
    __syncthreads();
    u16* dst = xt + ((size_t)n * XPP + (h + 1) * XP + 1) * 128;
    #pragma unroll
    for (int it = 0; it < 4; ++it) {
        int i = tid + it * 256;
        if (i < 56 * 16) {
            int w = i >> 4, oc = i & 15;
            union { u16 us[8]; uint4 v4; } pk;
            #pragma unroll
            for (int j = 0; j < 8; ++j) pk.us[j] = f2bf(T[oc * 8 + j][w]);
            *(uint4*)(dst + (size_t)w * 128 + oc * 8) = pk.v4;
        }
    }
}

// ===== 8-phase counted-vmcnt implicit-GEMM conv =====
// BM=256(all ch) x BN=256 pix x BK=64, 8 waves (2M x 4N, 128x64 each), 18 K-tiles, 9 iters.
// LDS: [buf2][half4][8192 u16]; halves 0=A_k0,1=A_k1,2=B_k0,3=B_k1; each [oct4][256 rows][8].
// Even tiles -> buf0, odd -> buf1. Per phase: stage the half that died at prev barrier.
__global__ __launch_bounds__(512, 2) void conv8(const u16* __restrict__ xt,
                                                const u16* __restrict__ wqt2,
                                                float* __restrict__ out,
                                                float* __restrict__ P) {
    __shared__ __align__(16) u16 lds[2][4][8192];   // 128 KB
    const int tid = threadIdx.x;
    const int lane = tid & 63;
    const int w8 = tid >> 6;
    const int wm = w8 >> 2, wn = w8 & 3;
    const int fr = lane & 15, fq = lane >> 4;
    // XCD swizzle (392 = 8*49, divisible -> bijective)
    const int nt = (blockIdx.x & 7) * 49 + (blockIdx.x >> 3);
    const int pixbase = nt * 256;

    // B staging roles: wave w8 -> oct4 = w8>>1, pixel groups {pg0, pg0+1}
    const int octB = w8 >> 1;
    const int pg0 = (w8 & 1) * 2;
    u32 site[2];
    #pragma unroll
    for (int r = 0; r < 2; ++r) {
        int p = pixbase + (pg0 + r) * 64 + lane;
        int n = p / HW2; int hw = p - n * HW2;
        int h = hw / HWD; int ww = hw - h * HWD;
        site[r] = (u32)(n * XT_PER_N + (h * XP + ww) * 128);
    }

#define STAGE_A(bf, S, kh) do {                                                  \
        const u16* g_ = wqt2 + (S) * 16384 + (kh) * 8192 + (w8 * 2) * 512 + lane * 8; \
        glds16(g_,       &lds[bf][kh][(w8 * 2 + 0) * 512]);                      \
        glds16(g_ + 512, &lds[bf][kh][(w8 * 2 + 1) * 512]);                      \
    } while (0)
#define STAGE_B(bf, S, kh) do {                                                  \
        int tap_ = (S) >> 1, ch_ = (S) & 1;                                      \
        int r_ = tap_ / 3, s_ = tap_ - r_ * 3;                                   \
        u32 off_ = (u32)((r_ * XP + s_) * 128 + ch_ * 64 + (kh) * 32 + octB * 8);\
        glds16(xt + site[0] + off_, &lds[bf][2 + (kh)][(octB * 4 + pg0 + 0) * 512]); \
        glds16(xt + site[1] + off_, &lds[bf][2 + (kh)][(octB * 4 + pg0 + 1) * 512]); \
    } while (0)
#define LOAD_A(dst, bf, kh, h_)                                                   \
        _Pragma("unroll") for (int mi = 0; mi < 4; ++mi)                          \
            dst[mi] = *(const short8*)&lds[bf][kh][fq * 2048 + ((size_t)(wm * 128 + (h_) * 64 + mi * 16 + fr)) * 8];
#define LOAD_B(dst, bf, kh)                                                       \
        _Pragma("unroll") for (int ni = 0; ni < 4; ++ni)                          \
            dst[ni] = *(const short8*)&lds[bf][2 + (kh)][fq * 2048 + ((size_t)(wn * 64 + ni * 16 + fr)) * 8];
#define MMA(h_, af_, bf_) do {                                                    \
        __builtin_amdgcn_s_setprio(1);                                            \
        _Pragma("unroll") for (int mi = 0; mi < 4; ++mi)                          \
            _Pragma("unroll") for (int ni = 0; ni < 4; ++ni)                      \
                acc[(h_) * 4 + mi][ni] = __builtin_amdgcn_mfma_f32_16x16x32_bf16( \
                    af_[mi], bf_[ni], acc[(h_) * 4 + mi][ni], 0, 0, 0);           \
        __builtin_amdgcn_s_setprio(0);                                            \
    } while (0)
#define BAR() __builtin_amdgcn_s_barrier()
#define WLG0() asm volatile("s_waitcnt lgkmcnt(0)" ::: "memory")

    f32x4 acc[8][4];
    #pragma unroll
    for (int a = 0; a < 8; ++a)
        #pragma unroll
        for (int b = 0; b < 4; ++b)
            acc[a][b] = (f32x4){0.f, 0.f, 0.f, 0.f};

    // prologue: tile0 all 4 halves, tile1 {B_k0, A_k0, B_k1}; A_k1(t1) staged at P1.
    STAGE_A(0, 0, 0); STAGE_A(0, 0, 1); STAGE_B(0, 0, 0); STAGE_B(0, 0, 1);
    STAGE_B(1, 1, 0); STAGE_A(1, 1, 0); STAGE_B(1, 1, 1);
    asm volatile("s_waitcnt vmcnt(6)" ::: "memory");   // tile0 landed; t1's 6 in flight
    BAR();

    #pragma unroll 1
    for (int i = 0; i < 9; ++i) {
        const int t2 = 2 * i + 2, t3 = 2 * i + 3;
        const bool st = (i < 8);
        short8 a0[4], a1[4], b0[4], b1[4];
        // P1: tile 2i (buf0), m-half0, k0
        LOAD_A(a0, 0, 0, 0); LOAD_B(b0, 0, 0);
        STAGE_A(1, 2 * i + 1, 1);                 // A_k1 of odd tile (always valid)
        BAR(); WLG0(); MMA(0, a0, b0); BAR();
        // P2: m-half1, k0
        LOAD_A(a1, 0, 0, 1);
        if (st) STAGE_B(0, t2, 0);
        BAR(); WLG0(); MMA(1, a1, b0); BAR();
        // P3: m-half0, k1
        LOAD_A(a0, 0, 1, 0); LOAD_B(b1, 0, 1);
        if (st) STAGE_A(0, t2, 0);
        BAR(); WLG0(); MMA(0, a0, b1); BAR();
        // P4: m-half1, k1  (guard for P5's reads of tile 2i+1)
        if (i == 8) asm volatile("s_waitcnt vmcnt(0)" ::: "memory");
        else        asm volatile("s_waitcnt vmcnt(4)" ::: "memory");
        LOAD_A(a1, 0, 1, 1);
        if (st) STAGE_B(0, t2, 1);
        BAR(); WLG0(); MMA(1, a1, b1); BAR();
        // P5: tile 2i+1 (buf1), m-half0, k0
        LOAD_A(a0, 1, 0, 0); LOAD_B(b0, 1, 0);
        if (st) STAGE_A(0, t2, 1);
        BAR(); WLG0(); MMA(0, a0, b0); BAR();
        // P6: m-half1, k0
        LOAD_A(a1, 1, 0, 1);
        if (st) STAGE_B(1, t3, 0);
        BAR(); WLG0(); MMA(1, a1, b0); BAR();
        // P7: m-half0, k1
        LOAD_A(a0, 1, 1, 0); LOAD_B(b1, 1, 1);
        if (st) STAGE_A(1, t3, 0);
        BAR(); WLG0(); MMA(0, a0, b1); BAR();
        // P8: m-half1, k1  (guard for next-iter P1 reads of tile 2i+2)
        if (i == 8) asm volatile("s_waitcnt vmcnt(0)" ::: "memory");
        else        asm volatile("s_waitcnt vmcnt(4)" ::: "memory");
        LOAD_A(a1, 1, 1, 1);
        if (st) STAGE_B(1, t3, 1);
        BAR(); WLG0(); MMA(1, a1, b1); BAR();
    }
#undef STAGE_A
#undef STAGE_B
#undef LOAD_A
#undef LOAD_B
#undef MMA
#undef BAR
#undef WLG0

    // epilogue: C/D col(lane&15)=pixel, row((lane>>4)*4+j)=channel
    #pragma unroll
    for (int ni = 0; ni < 4; ++ni) {
        int pix = pixbase + wn * 64 + ni * 16 + fr;
        int n = pix / HW2;
        int hw = pix - n * HW2;
        int obase = n * CHW_OUT + hw;
        #pragma unroll
        for (int h = 0; h < 2; ++h)
            #pragma unroll
            for (int mi = 0; mi < 4; ++mi) {
                int ch = wm * 128 + h * 64 + mi * 16 + fq * 4;
                #pragma unroll
                for (int j = 0; j < 4; ++j)
                    out[obase + (ch + j) * HW2] = acc[h * 4 + mi][ni][j];
            }
    }

    // fused per-channel partials over this wave's 64 pixels (16 pixel-lanes x 4 ni)
    #pragma unroll
    for (int h = 0; h < 2; ++h)
        #pragma unroll
        for (int mi = 0; mi < 4; ++mi)
            #pragma unroll
            for (int j = 0; j < 4; ++j) {
                float s = 0.f, q = 0.f;
                #pragma unroll
                for (int ni = 0; ni < 4; ++ni) {
                    float v = acc[h * 4 + mi][ni][j];
                    s += v; q += v * v;
                }
                #pragma unroll
                for (int msk = 1; msk < 16; msk <<= 1) {
                    s += __shfl_xor(s, msk);
                    q += __shfl_xor(q, msk);
                }
                if (fr == 0) {
                    int ch = wm * 128 + h * 64 + mi * 16 + fq * 4 + j;
                    float* dst = P + ((size_t)(nt * 4 + wn) * 256 + ch) * 2;
                    dst[0] = s; dst[1] = q;
                }
            }
}

__global__ void stats_fin(const float* __restrict__ P, const float* __restrict__ gamma,
                          const float* __restrict__ beta, float* __restrict__ stats) {
    int ch = blockIdx.x;
    int tid = threadIdx.x;
    float s = 0.f, q = 0.f;
    for (int i = tid; i < NT2; i += 256) {
        const float* p = P + ((size_t)i * 256 + ch) * 2;
        s += p[0]; q += p[1];
    }
    for (int m = 32; m; m >>= 1) { s += __shfl_xor(s, m); q += __shfl_xor(q, m); }
    __shared__ float ss[4], qs[4];
    int l = tid & 63, w = tid >> 6;
    if (l == 0) { ss[w] = s; qs[w] = q; }
    __syncthreads();
    if (tid == 0) {
        float S = ss[0] + ss[1] + ss[2] + ss[3];
        float Q = qs[0] + qs[1] + qs[2] + qs[3];
        float mean = S / (float)PIX;
        float var = Q / (float)PIX - mean * mean;
        float inv = gamma[ch] * rsqrtf(var + 1e-5f);
        stats[2 * ch] = inv;
        stats[2 * ch + 1] = beta[ch] - mean * inv;
    }
}

__global__ void bn_relu_k(float* __restrict__ out, const float* __restrict__ stats) {
    const int n4 = (N_IMG * CHW_OUT) / 4;
    int stride = gridDim.x * blockDim.x;
    for (int i = blockIdx.x * blockDim.x + threadIdx.x; i < n4; i += stride) {
        int ch = (i / (HW2 / 4)) & (K_OUT - 1);
        float inv = stats[2 * ch], sh = stats[2 * ch + 1];
        f32x4 v = ((f32x4*)out)[i];
        #pragma unroll
        for (int j = 0; j < 4; ++j)
            v[j] = fmaxf(v[j] * inv + sh, 0.f);
        ((f32x4*)out)[i] = v;
    }
}

extern "C" void kernel_launch(void* const* d_in, const int* in_sizes, int n_in,
                              void* d_out, int out_size, void* d_ws, size_t ws_size,
                              hipStream_t stream) {
    const float* x = (const float*)d_in[0];
    const float* w = (const float*)d_in[1];
    const float* gamma = (const float*)d_in[2];
    const float* beta = (const float*)d_in[3];
    float* out = (float*)d_out;

    char* ws = (char*)d_ws;
    u32* wsmax = (u32*)ws;                         // [0, 64)
    float* stats = (float*)(ws + 64);              // 2KB
    u16* wqt2 = (u16*)(ws + 4096);                 // 589,824 B
    u16* xt = (u16*)(ws + (1u << 20));             // 27,557,888 B
    float* P = (float*)(ws + 29360128u);           // 3,211,264 B

    hipMemsetAsync(wsmax, 0, 64, stream);
    maxabs_k<<<128, 256, 0, stream>>>(w, wsmax);
    quant_t_k<<<WQ_N / 256, 256, 0, stream>>>(w, wsmax, wqt2);
    halo_zero<<<456, 256, 0, stream>>>(xt);
    pad_transpose<<<N_IMG * HWD, 256, 0, stream>>>(x, xt);
    conv8<<<392, 512, 0, stream>>>(xt, wqt2, out, P);
    stats_fin<<<K_OUT, 256, 0, stream>>>(P, gamma, beta, stats);
    bn_relu_k<<<4096, 256, 0, stream>>>(out, stats);
}

// Round 5
// 147.506 us; speedup vs baseline: 2.8837x; 1.0919x over previous
//
#include <hip/hip_runtime.h>

typedef unsigned short u16;
typedef unsigned int u32;
typedef __attribute__((ext_vector_type(4))) float f32x4;
typedef __attribute__((ext_vector_type(8))) short short8;

#define HWD 56
#define HW2 3136
#define C_IN 128
#define K_OUT 256
#define N_IMG 32
#define CHW_IN 401408   // 128*3136
#define CHW_OUT 802816  // 256*3136
#define PIX 100352      // 32*3136
#define WQ_N 294912     // 256*128*9
#define XP 58
#define XPP 3364        // 58*58
#define XT_PER_N (XPP*128)          // 430592 elems per image
#define NT2 1568        // stats slices: 392 blocks * 4 wn
#define CV_OFF 33554432u            // cvout offset in ws (32MB)
#define WS_NEED_BF16 (CV_OFF + (size_t)PIX * K_OUT * 2)

__device__ __forceinline__ u16 f2bf(float f) {
    u32 u = __float_as_uint(f);
    u32 r = u + 0x7FFFu + ((u >> 16) & 1u);
    return (u16)(r >> 16);
}

__device__ __forceinline__ void glds16(const u16* g, u16* l) {
    __builtin_amdgcn_global_load_lds(
        (const __attribute__((address_space(1))) void*)g,
        (__attribute__((address_space(3))) void*)l, 16, 0, 0);
}

__global__ void maxabs_k(const float* __restrict__ w, u32* __restrict__ wsmax) {
    float m = 0.f;
    for (int i = blockIdx.x * blockDim.x + threadIdx.x; i < WQ_N; i += gridDim.x * blockDim.x)
        m = fmaxf(m, fabsf(w[i]));
    for (int off = 32; off; off >>= 1)
        m = fmaxf(m, __shfl_xor(m, off));
    __shared__ float sm[4];
    int lane = threadIdx.x & 63, wid = threadIdx.x >> 6;
    if (lane == 0) sm[wid] = m;
    __syncthreads();
    if (threadIdx.x == 0) {
        float mm = fmaxf(fmaxf(sm[0], sm[1]), fmaxf(sm[2], sm[3]));
        atomicMax(wsmax, __float_as_uint(mm));
    }
}

// wqt2 layout: [kt(18)][oct8][m(256)][8] — matches conv LDS A layout exactly.
__global__ void quant_t_k(const float* __restrict__ w, const u32* __restrict__ wsmax,
                          u16* __restrict__ wqt2) {
    int o = blockIdx.x * 256 + threadIdx.x;
    if (o >= WQ_N) return;
    int j = o & 7;
    int t = o >> 3;
    int m = t & 255;
    int t2 = t >> 8;
    int oct8 = t2 & 7;
    int kt = t2 >> 3;
    int c = (kt & 1) * 64 + (oct8 >> 2) * 32 + (oct8 & 3) * 8 + j;
    int tap = kt >> 1;
    float scale = __uint_as_float(wsmax[0]) / 7.0f;
    float q = rintf(w[(m * 128 + c) * 9 + tap] / scale);
    q = fminf(fmaxf(q, -7.0f), 7.0f);
    wqt2[o] = f2bf(q * scale);
}

// zero only the 1-pixel halo of xt
__global__ void halo_zero(u16* __restrict__ xt) {
    int i = blockIdx.x * 256 + threadIdx.x;
    if (i >= 32 * 3648) return;
    int n = i / 3648, t = i - n * 3648;
    int site = t >> 4, chunk = t & 15;
    int h, w;
    if (site < 58)       { h = 0;          w = site; }
    else if (site < 116) { h = 57;         w = site - 58; }
    else if (site < 172) { h = site - 115; w = 0; }
    else                 { h = site - 171; w = 57; }
    *(uint4*)(xt + ((size_t)n * XPP + h * XP + w) * 128 + chunk * 8) = (uint4){0, 0, 0, 0};
}

// x (NCHW f32) -> xt (N,58,58,C) bf16 interior
__global__ __launch_bounds__(256) void pad_transpose(const float* __restrict__ x,
                                                     u16* __restrict__ xt) {
    __shared__ float T[128][57];
    const int tid = threadIdx.x;
    const int n = blockIdx.x / HWD;
    const int h = blockIdx.x - n * HWD;
    const float* src = x + (size_t)n * CHW_IN + h * HWD;
    #pragma unroll
    for (int it = 0; it < 7; ++it) {
        int i = tid + it * 256;
        int c = i / 14, q = i - c * 14;
        float4 v = *(const float4*)(src + c * HW2 + q * 4);
        T[c][q * 4 + 0] = v.x; T[c][q * 4 + 1] = v.y;
        T[c][q * 4 + 2] = v.z; T[c][q * 4 + 3] = v.w;
    }
    __syncthreads();
    u16* dst = xt + ((size_t)n * XPP + (h + 1) * XP + 1) * 128;
    #pragma unroll
    for (int it = 0; it < 4; ++it) {
        int i = tid + it * 256;
        if (i < 56 * 16) {
            int w = i >> 4, oc = i & 15;
            union { u16 us[8]; uint4 v4; } pk;
            #pragma unroll
            for (int j = 0; j < 8; ++j) pk.us[j] = f2bf(T[oc * 8 + j][w]);
            *(uint4*)(dst + (size_t)w * 128 + oc * 8) = pk.v4;
        }
    }
}

// ===== 8-phase, read-ahead pipelined implicit-GEMM conv =====
// MFMA(p) consumes frags ds_read at p-1; reads(p+1) issue before MMA(p); lgkm(0) after.
// One barrier per phase (all stage-target gaps = 2 phases; drift < 1 phase => safe).
template <bool BF16OUT>
__global__ __launch_bounds__(512, 2) void conv8(const u16* __restrict__ xt,
                                                const u16* __restrict__ wqt2,
                                                float* __restrict__ out,
                                                u16* __restrict__ cvout,
                                                float* __restrict__ P) {
    __shared__ __align__(16) u16 lds[2][4][8192];   // 128 KB
    const int tid = threadIdx.x;
    const int lane = tid & 63;
    const int w8 = tid >> 6;
    const int wm = w8 >> 2, wn = w8 & 3;
    const int fr = lane & 15, fq = lane >> 4;
    const int nt = (blockIdx.x & 7) * 49 + (blockIdx.x >> 3);   // XCD swizzle, bijective
    const int pixbase = nt * 256;

    const int octB = w8 >> 1;
    const int pg0 = (w8 & 1) * 2;
    u32 site[2];
    #pragma unroll
    for (int r = 0; r < 2; ++r) {
        int p = pixbase + (pg0 + r) * 64 + lane;
        int n = p / HW2; int hw = p - n * HW2;
        int h = hw / HWD; int ww = hw - h * HWD;
        site[r] = (u32)(n * XT_PER_N + (h * XP + ww) * 128);
    }

#define STAGE_A(bf, S, kh) do {                                                  \
        const u16* g_ = wqt2 + (S) * 16384 + (kh) * 8192 + (w8 * 2) * 512 + lane * 8; \
        glds16(g_,       &lds[bf][kh][(w8 * 2 + 0) * 512]);                      \
        glds16(g_ + 512, &lds[bf][kh][(w8 * 2 + 1) * 512]);                      \
    } while (0)
#define STAGE_B(bf, S, kh) do {                                                  \
        int tap_ = (S) >> 1, ch_ = (S) & 1;                                      \
        int r_ = tap_ / 3, s_ = tap_ - r_ * 3;                                   \
        u32 off_ = (u32)((r_ * XP + s_) * 128 + ch_ * 64 + (kh) * 32 + octB * 8);\
        glds16(xt + site[0] + off_, &lds[bf][2 + (kh)][(octB * 4 + pg0 + 0) * 512]); \
        glds16(xt + site[1] + off_, &lds[bf][2 + (kh)][(octB * 4 + pg0 + 1) * 512]); \
    } while (0)
#define LOAD_A(dst, bf, kh, h_)                                                   \
        _Pragma("unroll") for (int mi = 0; mi < 4; ++mi)                          \
            dst[mi] = *(const short8*)&lds[bf][kh][fq * 2048 + ((size_t)(wm * 128 + (h_) * 64 + mi * 16 + fr)) * 8];
#define LOAD_B(dst, bf, kh)                                                       \
        _Pragma("unroll") for (int ni = 0; ni < 4; ++ni)                          \
            dst[ni] = *(const short8*)&lds[bf][2 + (kh)][fq * 2048 + ((size_t)(wn * 64 + ni * 16 + fr)) * 8];
#define MMA(h_, af_, bf_) do {                                                    \
        __builtin_amdgcn_s_setprio(1);                                            \
        _Pragma("unroll") for (int mi = 0; mi < 4; ++mi)                          \
            _Pragma("unroll") for (int ni = 0; ni < 4; ++ni)                      \
                acc[(h_) * 4 + mi][ni] = __builtin_amdgcn_mfma_f32_16x16x32_bf16( \
                    af_[mi], bf_[ni], acc[(h_) * 4 + mi][ni], 0, 0, 0);           \
        __builtin_amdgcn_s_setprio(0);                                            \
    } while (0)
#define BAR() __builtin_amdgcn_s_barrier()
#define WLG0() asm volatile("s_waitcnt lgkmcnt(0)" ::: "memory")
#define SCHED0() __builtin_amdgcn_sched_barrier(0)
#define GATE(n_) asm volatile("s_waitcnt vmcnt(" #n_ ")" ::: "memory")

    f32x4 acc[8][4];
    #pragma unroll
    for (int a = 0; a < 8; ++a)
        #pragma unroll
        for (int b = 0; b < 4; ++b)
            acc[a][b] = (f32x4){0.f, 0.f, 0.f, 0.f};

    short8 ra[4], rna[4], rb[4], rnb[4];

    // prologue: tile0 all halves, tile1 {B_k0, A_k0, B_k1}; A_k1(t1) staged at P1.
    STAGE_A(0, 0, 0); STAGE_A(0, 0, 1); STAGE_B(0, 0, 0); STAGE_B(0, 0, 1);
    STAGE_B(1, 1, 0); STAGE_A(1, 1, 0); STAGE_B(1, 1, 1);
    GATE(6);           // tile0 (this wave's part) landed; barrier makes it block-wide
    BAR();
    LOAD_A(ra, 0, 0, 0); LOAD_B(rb, 0, 0);
    WLG0(); SCHED0();

    #pragma unroll 1
    for (int i = 0; i < 9; ++i) {
        const int t2 = 2 * i + 2, t3 = 2 * i + 3;
        const bool st = (i < 8);
        // P1: MFMA buf0 k0 h0; read A0k0h1
        STAGE_A(1, 2 * i + 1, 1);
        LOAD_A(rna, 0, 0, 1);
        SCHED0(); MMA(0, ra, rb); WLG0(); SCHED0(); BAR();
        // P2: MFMA h1 k0; read A0k1h0 + B0k1
        if (st) STAGE_B(0, t2, 0);
        LOAD_A(ra, 0, 1, 0); LOAD_B(rnb, 0, 1);
        SCHED0(); MMA(1, rna, rb); WLG0(); SCHED0(); BAR();
        // P3: MFMA h0 k1; read A0k1h1
        if (st) STAGE_A(0, t2, 0);
        LOAD_A(rna, 0, 1, 1);
        SCHED0(); MMA(0, ra, rnb); WLG0(); SCHED0(); BAR();
        // P4: gate buf1; MFMA h1 k1; read buf1 A1k0h0 + B1k0
        if (i == 8) GATE(0); else GATE(4);
        if (st) STAGE_B(0, t2, 1);
        LOAD_A(ra, 1, 0, 0); LOAD_B(rb, 1, 0);
        SCHED0(); MMA(1, rna, rnb); WLG0(); SCHED0(); BAR();
        // P5: MFMA buf1 k0 h0; read A1k0h1
        if (st) STAGE_A(0, t2, 1);
        LOAD_A(rna, 1, 0, 1);
        SCHED0(); MMA(0, ra, rb); WLG0(); SCHED0(); BAR();
        // P6: MFMA h1 k0; read A1k1h0 + B1k1
        if (st) STAGE_B(1, t3, 0);
        LOAD_A(ra, 1, 1, 0); LOAD_B(rnb, 1, 1);
        SCHED0(); MMA(1, rna, rb); WLG0(); SCHED0(); BAR();
        // P7: MFMA h0 k1; read A1k1h1
        if (st) STAGE_A(1, t3, 0);
        LOAD_A(rna, 1, 1, 1);
        SCHED0(); MMA(0, ra, rnb); WLG0(); SCHED0(); BAR();
        // P8: gate buf0(t2); MFMA h1 k1; read next-iter buf0 frags
        if (i == 8) GATE(0); else GATE(4);
        if (st) {
            STAGE_B(1, t3, 1);
            LOAD_A(ra, 0, 0, 0); LOAD_B(rb, 0, 0);
        }
        SCHED0(); MMA(1, rna, rnb); WLG0(); SCHED0(); BAR();
    }
#undef STAGE_A
#undef STAGE_B
#undef LOAD_A
#undef LOAD_B
#undef MMA
#undef BAR
#undef WLG0
#undef SCHED0
#undef GATE

    // epilogue: C/D col(lane&15)=pixel, row((lane>>4)*4+j)=channel
    #pragma unroll
    for (int ni = 0; ni < 4; ++ni) {
        int pix = pixbase + wn * 64 + ni * 16 + fr;
        int n = pix / HW2;
        int hw = pix - n * HW2;
        size_t obase = (size_t)n * CHW_OUT + hw;
        #pragma unroll
        for (int h = 0; h < 2; ++h)
            #pragma unroll
            for (int mi = 0; mi < 4; ++mi) {
                int ch = wm * 128 + h * 64 + mi * 16 + fq * 4;
                #pragma unroll
                for (int j = 0; j < 4; ++j) {
                    if (BF16OUT)
                        cvout[obase + (size_t)(ch + j) * HW2] = f2bf(acc[h * 4 + mi][ni][j]);
                    else
                        out[obase + (size_t)(ch + j) * HW2] = acc[h * 4 + mi][ni][j];
                }
            }
    }

    // fused per-channel partials (P layout: [ch][slice][2] for coalesced finish)
    const int slice = nt * 4 + wn;
    #pragma unroll
    for (int h = 0; h < 2; ++h)
        #pragma unroll
        for (int mi = 0; mi < 4; ++mi)
            #pragma unroll
            for (int j = 0; j < 4; ++j) {
                float s = 0.f, q = 0.f;
                #pragma unroll
                for (int ni = 0; ni < 4; ++ni) {
                    float v = acc[h * 4 + mi][ni][j];
                    s += v; q += v * v;
                }
                #pragma unroll
                for (int msk = 1; msk < 16; msk <<= 1) {
                    s += __shfl_xor(s, msk);
                    q += __shfl_xor(q, msk);
                }
                if (fr == 0) {
                    int ch = wm * 128 + h * 64 + mi * 16 + fq * 4 + j;
                    float* dst = P + ((size_t)ch * NT2 + slice) * 2;
                    dst[0] = s; dst[1] = q;
                }
            }
}

__global__ void stats_fin(const float* __restrict__ P, const float* __restrict__ gamma,
                          const float* __restrict__ beta, float* __restrict__ stats) {
    int ch = blockIdx.x;
    int tid = threadIdx.x;
    float s = 0.f, q = 0.f;
    const float* base = P + (size_t)ch * NT2 * 2;
    for (int i = tid; i < NT2; i += 256) {
        float2 v = *(const float2*)(base + i * 2);
        s += v.x; q += v.y;
    }
    for (int m = 32; m; m >>= 1) { s += __shfl_xor(s, m); q += __shfl_xor(q, m); }
    __shared__ float ss[4], qs[4];
    int l = tid & 63, w = tid >> 6;
    if (l == 0) { ss[w] = s; qs[w] = q; }
    __syncthreads();
    if (tid == 0) {
        float S = ss[0] + ss[1] + ss[2] + ss[3];
        float Q = qs[0] + qs[1] + qs[2] + qs[3];
        float mean = S / (float)PIX;
        float var = Q / (float)PIX - mean * mean;
        float inv = gamma[ch] * rsqrtf(var + 1e-5f);
        stats[2 * ch] = inv;
        stats[2 * ch + 1] = beta[ch] - mean * inv;
    }
}

__global__ void bn_relu_f32(float* __restrict__ out, const float* __restrict__ stats) {
    const int n4 = (N_IMG * CHW_OUT) / 4;
    int stride = gridDim.x * blockDim.x;
    for (int i = blockIdx.x * blockDim.x + threadIdx.x; i < n4; i += stride) {
        int ch = (i / (HW2 / 4)) & (K_OUT - 1);
        float inv = stats[2 * ch], sh = stats[2 * ch + 1];
        f32x4 v = ((f32x4*)out)[i];
        #pragma unroll
        for (int j = 0; j < 4; ++j)
            v[j] = fmaxf(v[j] * inv + sh, 0.f);
        ((f32x4*)out)[i] = v;
    }
}

__global__ void bn_relu_bf16(const u16* __restrict__ cvout, float* __restrict__ out,
                             const float* __restrict__ stats) {
    const int n8 = (N_IMG * CHW_OUT) / 8;
    int stride = gridDim.x * blockDim.x;
    for (int i = blockIdx.x * blockDim.x + threadIdx.x; i < n8; i += stride) {
        int ch = (i / (HW2 / 8)) & (K_OUT - 1);
        float inv = stats[2 * ch], sh = stats[2 * ch + 1];
        short8 v = ((const short8*)cvout)[i];
        f32x4 o0, o1;
        #pragma unroll
        for (int j = 0; j < 4; ++j) {
            float a = __uint_as_float(((u32)(u16)v[j]) << 16);
            float b = __uint_as_float(((u32)(u16)v[j + 4]) << 16);
            o0[j] = fmaxf(a * inv + sh, 0.f);
            o1[j] = fmaxf(b * inv + sh, 0.f);
        }
        ((f32x4*)out)[i * 2] = o0;
        ((f32x4*)out)[i * 2 + 1] = o1;
    }
}

extern "C" void kernel_launch(void* const* d_in, const int* in_sizes, int n_in,
                              void* d_out, int out_size, void* d_ws, size_t ws_size,
                              hipStream_t stream) {
    const float* x = (const float*)d_in[0];
    const float* w = (const float*)d_in[1];
    const float* gamma = (const float*)d_in[2];
    const float* beta = (const float*)d_in[3];
    float* out = (float*)d_out;

    char* ws = (char*)d_ws;
    u32* wsmax = (u32*)ws;                         // [0, 64)
    float* stats = (float*)(ws + 64);              // 2KB
    u16* wqt2 = (u16*)(ws + 4096);                 // 589,824 B
    u16* xt = (u16*)(ws + (1u << 20));             // 27,557,888 B
    float* P = (float*)(ws + 29360128u);           // 3,211,264 B
    u16* cvout = (u16*)(ws + CV_OFF);              // 51,380,224 B (bf16 path)
    const bool bf16path = (ws_size >= WS_NEED_BF16);

    hipMemsetAsync(wsmax, 0, 64, stream);
    maxabs_k<<<128, 256, 0, stream>>>(w, wsmax);
    quant_t_k<<<WQ_N / 256, 256, 0, stream>>>(w, wsmax, wqt2);
    halo_zero<<<456, 256, 0, stream>>>(xt);
    pad_transpose<<<N_IMG * HWD, 256, 0, stream>>>(x, xt);
    if (bf16path) {
        conv8<true><<<392, 512, 0, stream>>>(xt, wqt2, out, cvout, P);
        stats_fin<<<K_OUT, 256, 0, stream>>>(P, gamma, beta, stats);
        bn_relu_bf16<<<4096, 256, 0, stream>>>(cvout, out, stats);
    } else {
        conv8<false><<<392, 512, 0, stream>>>(xt, wqt2, out, cvout, P);
        stats_fin<<<K_OUT, 256, 0, stream>>>(P, gamma, beta, stats);
        bn_relu_f32<<<4096, 256, 0, stream>>>(out, stats);
    }
}

// Round 6
// 146.963 us; speedup vs baseline: 2.8943x; 1.0037x over previous
//
#include <hip/hip_runtime.h>

typedef unsigned short u16;
typedef unsigned int u32;
typedef __attribute__((ext_vector_type(4))) float f32x4;
typedef __attribute__((ext_vector_type(8))) short short8;

#define HWD 56
#define HW2 3136
#define C_IN 128
#define K_OUT 256
#define N_IMG 32
#define CHW_IN 401408   // 128*3136
#define PIX 100352      // 32*3136
#define WQ_N 294912     // 256*128*9
#define XP 58
#define XPP 3364        // 58*58
#define XT_PER_N (XPP*128)          // 430592 elems per image
#define NSLICE 1568     // 784 nt * 2 wn
#define CV_OFF 33554432u            // cvout offset in ws (32MB)
#define WS_NEED_BF16 (CV_OFF + (size_t)PIX * K_OUT * 2)

__device__ __forceinline__ u16 f2bf(float f) {
    u32 u = __float_as_uint(f);
    u32 r = u + 0x7FFFu + ((u >> 16) & 1u);
    return (u16)(r >> 16);
}

__device__ __forceinline__ void glds16(const u16* g, u16* l) {
    __builtin_amdgcn_global_load_lds(
        (const __attribute__((address_space(1))) void*)g,
        (__attribute__((address_space(3))) void*)l, 16, 0, 0);
}

__global__ void maxabs_k(const float* __restrict__ w, u32* __restrict__ wsmax) {
    float m = 0.f;
    for (int i = blockIdx.x * blockDim.x + threadIdx.x; i < WQ_N; i += gridDim.x * blockDim.x)
        m = fmaxf(m, fabsf(w[i]));
    for (int off = 32; off; off >>= 1)
        m = fmaxf(m, __shfl_xor(m, off));
    __shared__ float sm[4];
    int lane = threadIdx.x & 63, wid = threadIdx.x >> 6;
    if (lane == 0) sm[wid] = m;
    __syncthreads();
    if (threadIdx.x == 0) {
        float mm = fmaxf(fmaxf(sm[0], sm[1]), fmaxf(sm[2], sm[3]));
        atomicMax(wsmax, __float_as_uint(mm));
    }
}

// wqt3 layout: [kt(36)][mt(2)][oct(4)][m(128)][8] — one contiguous 8KB A-tile per (kt,mt).
// kt = tap*4 + cq ; c = cq*32 + oct*8 + j ; m = mt*128 + mrow
__global__ void quant_t_k3(const float* __restrict__ w, const u32* __restrict__ wsmax,
                           u16* __restrict__ wqt3) {
    int o = blockIdx.x * 256 + threadIdx.x;
    if (o >= WQ_N) return;
    int j = o & 7;
    int r1 = o >> 3;
    int mrow = r1 & 127;
    int r2 = r1 >> 7;
    int oct = r2 & 3;
    int r3 = r2 >> 2;
    int mt = r3 & 1;
    int kt = r3 >> 1;
    int m = mt * 128 + mrow;
    int tap = kt >> 2, cq = kt & 3;
    int c = cq * 32 + oct * 8 + j;
    float scale = __uint_as_float(wsmax[0]) / 7.0f;
    float q = rintf(w[(m * 128 + c) * 9 + tap] / scale);
    q = fminf(fmaxf(q, -7.0f), 7.0f);
    wqt3[o] = f2bf(q * scale);
}

// zero only the 1-pixel halo of xt
__global__ void halo_zero(u16* __restrict__ xt) {
    int i = blockIdx.x * 256 + threadIdx.x;
    if (i >= 32 * 3648) return;
    int n = i / 3648, t = i - n * 3648;
    int site = t >> 4, chunk = t & 15;
    int h, w;
    if (site < 58)       { h = 0;          w = site; }
    else if (site < 116) { h = 57;         w = site - 58; }
    else if (site < 172) { h = site - 115; w = 0; }
    else                 { h = site - 171; w = 57; }
    *(uint4*)(xt + ((size_t)n * XPP + h * XP + w) * 128 + chunk * 8) = (uint4){0, 0, 0, 0};
}

// x (NCHW f32) -> xt (N,58,58,C) bf16 interior
__global__ __launch_bounds__(256) void pad_transpose(const float* __restrict__ x,
                                                     u16* __restrict__ xt) {
    __shared__ float T[128][57];
    const int tid = threadIdx.x;
    const int n = blockIdx.x / HWD;
    const int h = blockIdx.x - n * HWD;
    const float* src = x + (size_t)n * CHW_IN + h * HWD;
    #pragma unroll
    for (int it = 0; it < 7; ++it) {
        int i = tid + it * 256;
        int c = i / 14, q = i - c * 14;
        float4 v = *(const float4*)(src + c * HW2 + q * 4);
        T[c][q * 4 + 0] = v.x; T[c][q * 4 + 1] = v.y;
        T[c][q * 4 + 2] = v.z; T[c][q * 4 + 3] = v.w;
    }
    __syncthreads();
    u16* dst = xt + ((size_t)n * XPP + (h + 1) * XP + 1) * 128;
    #pragma unroll
    for (int it = 0; it < 4; ++it) {
        int i = tid + it * 256;
        if (i < 56 * 16) {
            int w = i >> 4, oc = i & 15;
            union { u16 us[8]; uint4 v4; } pk;
            #pragma unroll
            for (int j = 0; j < 8; ++j) pk.us[j] = f2bf(T[oc * 8 + j][w]);
            *(uint4*)(dst + (size_t)w * 128 + oc * 8) = pk.v4;
        }
    }
}

// ===== BM128 x BN128 x BK32, 3-buf depth-2 counted-vmcnt, 4 waves, 3 blocks/CU =====
// LDS buf: A [oct4][m128][8] (8KB) + B [oct4][px128][8] (8KB) = 16KB; 3 bufs = 48KB.
// Phase t: STAGE(t+2 -> buf[(t+2)%3]); ds_read(t); lgkm0; MMA; GATE(4) [forces t+1 landed]; BAR.
template <bool BF16OUT>
__global__ __launch_bounds__(256, 3) void conv_m(const u16* __restrict__ xt,
                                                 const u16* __restrict__ wqt3,
                                                 float* __restrict__ out,
                                                 u16* __restrict__ cvout,
                                                 float* __restrict__ P) {
    __shared__ __align__(16) u16 lds[3][2][4096];   // 48 KB
    const int tid = threadIdx.x;
    const int lane = tid & 63;
    const int w4 = tid >> 6;           // 4 waves, 2m x 2n
    const int wm = w4 >> 1, wn = w4 & 1;
    const int fr = lane & 15, fq = lane >> 4;
    // XCD swizzle: 1568 = 8*196, bijective
    const int swz = (blockIdx.x & 7) * 196 + (blockIdx.x >> 3);
    const int nt = swz >> 1, mt = swz & 1;   // mt-pairs adjacent -> share B tile in L2
    const int pixbase = nt * 128;

    // B staging sites: inst i covers px = i*64 + lane (all waves same px, different oct=w4)
    u32 siteE[2];
    #pragma unroll
    for (int i = 0; i < 2; ++i) {
        int p = pixbase + i * 64 + lane;
        int n = p / HW2; int hw = p - n * HW2;
        int h = hw / HWD; int ww = hw - h * HWD;
        siteE[i] = (u32)(n * XT_PER_N + (h * XP + ww) * 128);
    }

#define STAGE(AB, BB, kt_) do {                                                   \
        const int tap_ = (kt_) >> 2, cq_ = (kt_) & 3;                             \
        const int r_ = tap_ / 3, s_ = tap_ - r_ * 3;                              \
        const u16* ga_ = wqt3 + ((kt_) * 2 + mt) * 4096 + (w4 * 2) * 512 + lane * 8; \
        glds16(ga_,       (AB) + (w4 * 2 + 0) * 512);                             \
        glds16(ga_ + 512, (AB) + (w4 * 2 + 1) * 512);                             \
        const u32 be_ = (u32)((r_ * XP + s_) * 128 + cq_ * 32 + w4 * 8);          \
        glds16(xt + siteE[0] + be_, (BB) + w4 * 1024 + 0);                        \
        glds16(xt + siteE[1] + be_, (BB) + w4 * 1024 + 512);                      \
    } while (0)
#define PHASE_BODY(Acur, Bcur) do {                                               \
        short8 af[4], bf[4];                                                      \
        _Pragma("unroll") for (int mi = 0; mi < 4; ++mi)                          \
            af[mi] = *(const short8*)&(Acur)[fq * 1024 + (wm * 64 + mi * 16 + fr) * 8]; \
        _Pragma("unroll") for (int ni = 0; ni < 4; ++ni)                          \
            bf[ni] = *(const short8*)&(Bcur)[fq * 1024 + (wn * 64 + ni * 16 + fr) * 8]; \
        asm volatile("s_waitcnt lgkmcnt(0)" ::: "memory");                        \
        __builtin_amdgcn_sched_barrier(0);                                        \
        __builtin_amdgcn_s_setprio(1);                                            \
        _Pragma("unroll") for (int mi = 0; mi < 4; ++mi)                          \
            _Pragma("unroll") for (int ni = 0; ni < 4; ++ni)                      \
                acc[mi][ni] = __builtin_amdgcn_mfma_f32_16x16x32_bf16(            \
                    af[mi], bf[ni], acc[mi][ni], 0, 0, 0);                        \
        __builtin_amdgcn_s_setprio(0);                                            \
    } while (0)
#define BAR() __builtin_amdgcn_s_barrier()
#define GATE(n_) asm volatile("s_waitcnt vmcnt(" #n_ ")" ::: "memory")

    f32x4 acc[4][4];
    #pragma unroll
    for (int a = 0; a < 4; ++a)
        #pragma unroll
        for (int b = 0; b < 4; ++b)
            acc[a][b] = (f32x4){0.f, 0.f, 0.f, 0.f};

    // prologue: tiles 0,1 into bufs 0,1; keep tile1's 4 in flight
    STAGE(&lds[0][0][0], &lds[0][1][0], 0);
    STAGE(&lds[1][0][0], &lds[1][1][0], 1);
    GATE(4);
    BAR();

    #pragma unroll 1
    for (int tt = 0; tt < 12; ++tt) {
        #pragma unroll
        for (int u = 0; u < 3; ++u) {
            const int t = tt * 3 + u;
            const int bs = (u + 2) % 3;          // (t+2)%3
            if (t < 34) STAGE(&lds[bs][0][0], &lds[bs][1][0], t + 2);
            PHASE_BODY(&lds[u][0][0], &lds[u][1][0]);
            if (t < 34) GATE(4);
            else if (t == 34) GATE(0);
            BAR();
        }
    }
#undef STAGE
#undef PHASE_BODY
#undef GATE

    // ---- fused per-channel partials (before LDS is reused)
    const int slice = nt * 2 + wn;
    #pragma unroll
    for (int mi = 0; mi < 4; ++mi)
        #pragma unroll
        for (int j = 0; j < 4; ++j) {
            float s = 0.f, q = 0.f;
            #pragma unroll
            for (int ni = 0; ni < 4; ++ni) {
                float v = acc[mi][ni][j];
                s += v; q += v * v;
            }
            #pragma unroll
            for (int msk = 1; msk < 16; msk <<= 1) {
                s += __shfl_xor(s, msk);
                q += __shfl_xor(q, msk);
            }
            if (fr == 0) {
                int ch = mt * 128 + wm * 64 + mi * 16 + fq * 4 + j;
                float* dst = P + ((size_t)ch * NSLICE + slice) * 2;
                dst[0] = s; dst[1] = q;
            }
        }

    if (BF16OUT) {
        // ---- dense epilogue: LDS transpose to T[ch128][px 136pad], then 16B stores
        u16* T = (u16*)&lds[0][0][0];            // 128*136*2 = 34816 B
        #pragma unroll
        for (int mi = 0; mi < 4; ++mi)
            #pragma unroll
            for (int ni = 0; ni < 4; ++ni) {
                int px_l = wn * 64 + ni * 16 + fr;
                int ch_l = wm * 64 + mi * 16 + fq * 4;
                #pragma unroll
                for (int j = 0; j < 4; ++j)
                    T[(ch_l + j) * 136 + px_l] = f2bf(acc[mi][ni][j]);
            }
        __syncthreads();
        #pragma unroll
        for (int it = 0; it < 8; ++it) {
            int q = tid + it * 256;              // 2048 chunks
            int ch_l = q >> 4, pg = q & 15;
            uint4 v = *(const uint4*)&T[ch_l * 136 + pg * 8];
            *(uint4*)&cvout[(size_t)(mt * 128 + ch_l) * PIX + pixbase + pg * 8] = v;
        }
    } else {
        // fallback: direct scattered f32 NCHW
        #pragma unroll
        for (int ni = 0; ni < 4; ++ni) {
            int pix = pixbase + wn * 64 + ni * 16 + fr;
            int n = pix / HW2;
            int hw = pix - n * HW2;
            size_t obase = (size_t)n * (K_OUT * HW2) + hw;
            #pragma unroll
            for (int mi = 0; mi < 4; ++mi) {
                int ch = mt * 128 + wm * 64 + mi * 16 + fq * 4;
                #pragma unroll
                for (int j = 0; j < 4; ++j)
                    out[obase + (size_t)(ch + j) * HW2] = acc[mi][ni][j];
            }
        }
    }
#undef BAR
}

__global__ void stats_fin(const float* __restrict__ P, const float* __restrict__ gamma,
                          const float* __restrict__ beta, float* __restrict__ stats) {
    int ch = blockIdx.x;
    int tid = threadIdx.x;
    float s = 0.f, q = 0.f;
    const float* base = P + (size_t)ch * NSLICE * 2;
    for (int i = tid; i < NSLICE; i += 256) {
        float2 v = *(const float2*)(base + i * 2);
        s += v.x; q += v.y;
    }
    for (int m = 32; m; m >>= 1) { s += __shfl_xor(s, m); q += __shfl_xor(q, m); }
    __shared__ float ss[4], qs[4];
    int l = tid & 63, w = tid >> 6;
    if (l == 0) { ss[w] = s; qs[w] = q; }
    __syncthreads();
    if (tid == 0) {
        float S = ss[0] + ss[1] + ss[2] + ss[3];
        float Q = qs[0] + qs[1] + qs[2] + qs[3];
        float mean = S / (float)PIX;
        float var = Q / (float)PIX - mean * mean;
        float inv = gamma[ch] * rsqrtf(var + 1e-5f);
        stats[2 * ch] = inv;
        stats[2 * ch + 1] = beta[ch] - mean * inv;
    }
}

// cvout [ch][global-pix] bf16 -> out NCHW f32 (both sides dense)
__global__ void bn_relu_nchw(const u16* __restrict__ cvout, float* __restrict__ out,
                             const float* __restrict__ stats) {
    const int b = blockIdx.x;            // 256 ch * 49 groups
    const int ch = b / 49, g = b - ch * 49;
    const float inv = stats[2 * ch], sh = stats[2 * ch + 1];
    const int p8 = (g * 256 + threadIdx.x) * 8;   // 8-px chunk; 3136%8==0 -> never crosses n
    short8 v = *(const short8*)&cvout[(size_t)ch * PIX + p8];
    const int n = p8 / HW2;
    const int hw = p8 - n * HW2;
    float* dst = out + ((size_t)n * K_OUT + ch) * HW2 + hw;
    f32x4 o0, o1;
    #pragma unroll
    for (int j = 0; j < 4; ++j) {
        float a = __uint_as_float(((u32)(u16)v[j]) << 16);
        float bb = __uint_as_float(((u32)(u16)v[j + 4]) << 16);
        o0[j] = fmaxf(a * inv + sh, 0.f);
        o1[j] = fmaxf(bb * inv + sh, 0.f);
    }
    *(f32x4*)dst = o0;
    *(f32x4*)(dst + 4) = o1;
}

__global__ void bn_relu_f32(float* __restrict__ out, const float* __restrict__ stats) {
    const int n4 = ((size_t)N_IMG * K_OUT * HW2) / 4;
    int stride = gridDim.x * blockDim.x;
    for (int i = blockIdx.x * blockDim.x + threadIdx.x; i < n4; i += stride) {
        int ch = (i / (HW2 / 4)) & (K_OUT - 1);
        float inv = stats[2 * ch], sh = stats[2 * ch + 1];
        f32x4 v = ((f32x4*)out)[i];
        #pragma unroll
        for (int j = 0; j < 4; ++j)
            v[j] = fmaxf(v[j] * inv + sh, 0.f);
        ((f32x4*)out)[i] = v;
    }
}

extern "C" void kernel_launch(void* const* d_in, const int* in_sizes, int n_in,
                              void* d_out, int out_size, void* d_ws, size_t ws_size,
                              hipStream_t stream) {
    const float* x = (const float*)d_in[0];
    const float* w = (const float*)d_in[1];
    const float* gamma = (const float*)d_in[2];
    const float* beta = (const float*)d_in[3];
    float* out = (float*)d_out;

    char* ws = (char*)d_ws;
    u32* wsmax = (u32*)ws;                         // [0, 64)
    float* stats = (float*)(ws + 64);              // 2KB
    u16* wqt3 = (u16*)(ws + 4096);                 // 589,824 B
    u16* xt = (u16*)(ws + (1u << 20));             // 27,557,888 B
    float* P = (float*)(ws + 29360128u);           // 3,211,264 B (ends 32.57MB)
    u16* cvout = (u16*)(ws + CV_OFF);              // 51,380,224 B
    const bool bf16path = (ws_size >= WS_NEED_BF16);

    hipMemsetAsync(wsmax, 0, 64, stream);
    maxabs_k<<<128, 256, 0, stream>>>(w, wsmax);
    quant_t_k3<<<WQ_N / 256, 256, 0, stream>>>(w, wsmax, wqt3);
    halo_zero<<<456, 256, 0, stream>>>(xt);
    pad_transpose<<<N_IMG * HWD, 256, 0, stream>>>(x, xt);
    if (bf16path) {
        conv_m<true><<<1568, 256, 0, stream>>>(xt, wqt3, out, cvout, P);
        stats_fin<<<K_OUT, 256, 0, stream>>>(P, gamma, beta, stats);
        bn_relu_nchw<<<K_OUT * 49, 256, 0, stream>>>(cvout, out, stats);
    } else {
        conv_m<false><<<1568, 256, 0, stream>>>(xt, wqt3, out, cvout, P);
        stats_fin<<<K_OUT, 256, 0, stream>>>(P, gamma, beta, stats);
        bn_relu_f32<<<4096, 256, 0, stream>>>(out, stats);
    }
}